// Round 8
// baseline (155.694 us; speedup 1.0000x reference)
//
#include <hip/hip_runtime.h>
#include <hip/hip_bf16.h>

// Problem: B=4, L=2048, D_MODEL=1024, H=16, D_QKV=64.
// Reference einsum 'bhlk,blhd->blhd' contracts k over logits only; softmax sums to 1,
// so attention output == v and the net reduces to:
//   out = x @ Wc + fc_b,  Wc[m][j] = sum_{hd} w_v[h][m][d] * fc_w[j][hd]
// prep (512 blocks x 512 thr): blocks 0-255 fold Wc^T with split-K=2 + LDS reduction;
//                              blocks 256-511 cast x->bf16. Independent, overlapped.
// final_gemm (1024 blocks x 256 thr, 4/CU): 128x64 tile, BK=32, DOUBLE-BUFFERED LDS
//   with one barrier/iter — gld(k+1) lands during MFMA(k) instead of being drained
//   immediately (the single-buffer structure exposed full gld latency every iter).

typedef __attribute__((ext_vector_type(8))) short bf16x8;
typedef __attribute__((ext_vector_type(4))) float f32x4;

__device__ __forceinline__ f32x4 mfma16(bf16x8 a, bf16x8 b, f32x4 c) {
  return __builtin_amdgcn_mfma_f32_16x16x32_bf16(a, b, c, 0, 0, 0);
}

// fp32 -> bf16 bits, round-to-nearest-even
__device__ __forceinline__ unsigned short f2b(float f) {
  unsigned int u = __builtin_bit_cast(unsigned int, f);
  return (unsigned short)((u + 0x7fffu + ((u >> 16) & 1u)) >> 16);
}

__device__ __forceinline__ bf16x8 cvt8(float4 a, float4 b) {
  bf16x8 r;
  r[0] = (short)f2b(a.x); r[1] = (short)f2b(a.y); r[2] = (short)f2b(a.z); r[3] = (short)f2b(a.w);
  r[4] = (short)f2b(b.x); r[5] = (short)f2b(b.y); r[6] = (short)f2b(b.z); r[7] = (short)f2b(b.w);
  return r;
}

// async global->LDS, 16 B per lane (m97 pattern; LDS dest = wave-uniform base + lane*16)
__device__ __forceinline__ void gld_lds16(const void* g, void* l) {
  __builtin_amdgcn_global_load_lds((const __attribute__((address_space(1))) unsigned int*)g,
                                   (__attribute__((address_space(3))) unsigned int*)l, 16, 0, 0);
}

// prep: blocks 0-255 fold Wc^T (split-K=2); blocks 256-511 cast x->bf16.
__global__ __launch_bounds__(512) void prep(const float* __restrict__ x,
                                            const float* __restrict__ wv,
                                            const float* __restrict__ fcw,
                                            unsigned short* __restrict__ xb,
                                            unsigned short* __restrict__ wcT) {
  __shared__ f32x4 red[4][64][4];
  int bid = blockIdx.x, t = threadIdx.x;
  int wid = t >> 6, lane = t & 63, l16 = lane & 15, quad = lane >> 4;

  if (bid < 256) {
    // fold: wcT[j][m] = sum_{hd} fcw[j][hd] * wv[hd>>6][m][hd&63]; 64x64 tile.
    // 8 waves: (wk, wr, wc); wk splits K=1024 into halves; LDS reduction at end.
    int wk = wid >> 2, wr = (wid >> 1) & 1, wc = wid & 1;
    int row0 = (bid >> 4) * 64 + wr * 32;   // j
    int col0 = (bid & 15) * 64 + wc * 32;   // m
    f32x4 acc[2][2];
#pragma unroll
    for (int a = 0; a < 2; a++)
#pragma unroll
      for (int b = 0; b < 2; b++) acc[a][b] = (f32x4){0.f, 0.f, 0.f, 0.f};

    for (int k0 = wk * 512; k0 < wk * 512 + 512; k0 += 32) {
      int kk = k0 + quad * 8;
      int h = kk >> 6, d = kk & 63;
      bf16x8 af[2], bfr[2];
#pragma unroll
      for (int rt = 0; rt < 2; rt++) {
        const float* pa = fcw + (row0 + rt * 16 + l16) * 1024 + kk;
        af[rt] = cvt8(*reinterpret_cast<const float4*>(pa), *reinterpret_cast<const float4*>(pa + 4));
      }
#pragma unroll
      for (int ct = 0; ct < 2; ct++) {
        const float* pb = wv + h * 65536 + (col0 + ct * 16 + l16) * 64 + d;
        bfr[ct] = cvt8(*reinterpret_cast<const float4*>(pb), *reinterpret_cast<const float4*>(pb + 4));
      }
#pragma unroll
      for (int rt = 0; rt < 2; rt++)
#pragma unroll
        for (int ct = 0; ct < 2; ct++) acc[rt][ct] = mfma16(af[rt], bfr[ct], acc[rt][ct]);
    }

    if (wk == 1) {
#pragma unroll
      for (int rt = 0; rt < 2; rt++)
#pragma unroll
        for (int ct = 0; ct < 2; ct++) red[wid & 3][lane][rt * 2 + ct] = acc[rt][ct];
    }
    __syncthreads();
    if (wk == 0) {
#pragma unroll
      for (int rt = 0; rt < 2; rt++)
#pragma unroll
        for (int ct = 0; ct < 2; ct++) {
          f32x4 s = acc[rt][ct];
          f32x4 o = red[wid & 3][lane][rt * 2 + ct];
          int j0 = row0 + rt * 16 + quad * 4;
          int m = col0 + ct * 16 + l16;
#pragma unroll
          for (int r = 0; r < 4; r++) wcT[(j0 + r) * 1024 + m] = f2b(s[r] + o[r]);
        }
    }
  } else {
    // cast: x fp32 -> bf16, 32768 elems per block (contiguous), 16-B ld/st.
    int base0 = (bid - 256) << 15;
#pragma unroll
    for (int i = 0; i < 8; i++) {
      int idx = base0 + i * 4096 + t * 8;
      float4 a = *reinterpret_cast<const float4*>(x + idx);
      float4 b = *reinterpret_cast<const float4*>(x + idx + 4);
      *reinterpret_cast<bf16x8*>(xb + idx) = cvt8(a, b);
    }
  }
}

// out[i][j] = sum_m xb[i][m]*wcT[j][m] + fcb[j].  M=8192,N=1024,K=1024.
// 128x64 tile, BK=32, double-buffered LDS (24 KB), one barrier per K-iter,
// 1024 blocks N-fastest, 4 blocks/CU.
__global__ __launch_bounds__(256, 4) void final_gemm(const unsigned short* __restrict__ xb,
                                                     const unsigned short* __restrict__ wcT,
                                                     const float* __restrict__ fcb,
                                                     float* __restrict__ out) {
  __shared__ __align__(16) unsigned short As[2][128 * 32];  // 8 KB per buf
  __shared__ __align__(16) unsigned short Bs[2][64 * 32];   // 4 KB per buf
  int t = threadIdx.x, wid = t >> 6, lane = t & 63, l16 = lane & 15, quad = lane >> 4;
  int wr = wid >> 1, wc = wid & 1;
  int row0 = (blockIdx.x >> 4) * 128;   // M tile (64 of them)
  int col0 = (blockIdx.x & 15) * 64;    // N tile (16, fastest: B stays L2-hot)

  // staging: per k-slab, A = 8 x 1KB wave-chunks (wave w does blkA = w*2+j, j<2),
  //          B = 4 x 1KB (wave w does blkB = w). chunk blk covers rows [blk*16,+16),
  //          lane -> row blk*16 + (lane>>2), k-quad lane&3; LDS off = blk*1KB + lane*16.
  const unsigned short* ApG[2];
#pragma unroll
  for (int j = 0; j < 2; j++) {
    int blk = wid * 2 + j;
    ApG[j] = xb + (row0 + blk * 16 + (lane >> 2)) * 1024 + (lane & 3) * 8;
  }
  const unsigned short* BpG = wcT + (col0 + wid * 16 + (lane >> 2)) * 1024 + (lane & 3) * 8;

  f32x4 acc[4][2];
#pragma unroll
  for (int rt = 0; rt < 4; rt++)
#pragma unroll
    for (int ct = 0; ct < 2; ct++) acc[rt][ct] = (f32x4){0.f, 0.f, 0.f, 0.f};

  // prologue: stage slab 0 into buf 0
#pragma unroll
  for (int j = 0; j < 2; j++) gld_lds16(ApG[j], &As[0][(wid * 2 + j) * 512 + lane * 8]);
  gld_lds16(BpG, &Bs[0][wid * 512 + lane * 8]);

  for (int k = 0; k < 32; k++) {
    int buf = k & 1;
    __syncthreads();   // drains gld(slab k) [compiler vmcnt(0)] + prior ds_reads of buf
    if (k < 31) {
      int k1 = (k + 1) * 32;
#pragma unroll
      for (int j = 0; j < 2; j++)
        gld_lds16(ApG[j] + k1, &As[buf ^ 1][(wid * 2 + j) * 512 + lane * 8]);
      gld_lds16(BpG + k1, &Bs[buf ^ 1][wid * 512 + lane * 8]);
    }
    bf16x8 af[4], bfr[2];
#pragma unroll
    for (int rt = 0; rt < 4; rt++)
      af[rt] = *reinterpret_cast<const bf16x8*>(&As[buf][(wr * 64 + rt * 16 + l16) * 32 + quad * 8]);
#pragma unroll
    for (int ct = 0; ct < 2; ct++)
      bfr[ct] = *reinterpret_cast<const bf16x8*>(&Bs[buf][(wc * 32 + ct * 16 + l16) * 32 + quad * 8]);
#pragma unroll
    for (int rt = 0; rt < 4; rt++)
#pragma unroll
      for (int ct = 0; ct < 2; ct++)
        acc[rt][ct] = mfma16(af[rt], bfr[ct], acc[rt][ct]);
  }

#pragma unroll
  for (int ct = 0; ct < 2; ct++) {
    int j = col0 + wc * 32 + ct * 16 + l16;
    float bias = fcb[j];
#pragma unroll
    for (int rt = 0; rt < 4; rt++) {
      int i0 = row0 + wr * 64 + rt * 16 + quad * 4;
      f32x4 a = acc[rt][ct];
#pragma unroll
      for (int r = 0; r < 4; r++) out[(i0 + r) * 1024 + j] = a[r] + bias;
    }
  }
}

extern "C" void kernel_launch(void* const* d_in, const int* in_sizes, int n_in,
                              void* d_out, int out_size, void* d_ws, size_t ws_size,
                              hipStream_t stream) {
  const float* x   = (const float*)d_in[0];
  // d_in[1] mask, d_in[2] w_q, d_in[3] w_k: dead per reference semantics
  const float* wv  = (const float*)d_in[4];
  const float* fcw = (const float*)d_in[5];
  const float* fcb = (const float*)d_in[6];
  float* out = (float*)d_out;

  char* ws = (char*)d_ws;
  unsigned short* xb  = (unsigned short*)(ws);              // 16 MB (8192x1024 bf16)
  unsigned short* wcT = (unsigned short*)(ws + 16777216);   // 2 MB  (1024x1024 bf16)

  prep<<<512, 512, 0, stream>>>(x, wv, fcw, xb, wcT);
  final_gemm<<<1024, 256, 0, stream>>>(xb, wcT, fcb, out);
}